// Round 5
// baseline (326.921 us; speedup 1.0000x reference)
//
#include <hip/hip_runtime.h>
#include <hip/hip_bf16.h>

typedef unsigned short u16;
typedef unsigned int u32;
typedef __bf16 bf16x8 __attribute__((ext_vector_type(8)));
typedef float f32x4 __attribute__((ext_vector_type(4)));
typedef u16 u16x4 __attribute__((ext_vector_type(4)));
typedef u16 u16x8 __attribute__((ext_vector_type(8)));

#define N_    4096
#define H_    16
#define BH_   64
#define DIM_  1024
#define MTOK  16384

// global row bases (row = 64 bf16 elements): 64*cumn[l]
#define RB1 262144
#define RB2 393216
#define RB3 458752
#define RB4 491520
#define RB5 507904
#define RB6 516096

#define SBAR __builtin_amdgcn_s_barrier()
#define SCHED0 __builtin_amdgcn_sched_barrier(0)

__device__ __forceinline__ float bf2f(u16 u) {
  union { u32 i; float f; } x; x.i = ((u32)u) << 16; return x.f;
}
__device__ __forceinline__ u16 f2bf(float f) {
  union { float f; u32 i; } x; x.f = f;
  u32 r = x.i + 0x7fffu + ((x.i >> 16) & 1u);
  return (u16)(r >> 16);
}

__device__ __forceinline__ void gload_lds16(const u16* g, u16* l) {
  __builtin_amdgcn_global_load_lds(
      (const __attribute__((address_space(1))) void*)g,
      (__attribute__((address_space(3))) void*)l, 16, 0, 0);
}

// ---------------- convert hidden fp32 -> bf16 ----------------
__global__ __launch_bounds__(256) void k_hid2bf(const float* __restrict__ in,
                                                u16* __restrict__ out, int n4) {
  int i = blockIdx.x * 256 + threadIdx.x;
  if (i >= n4) return;
  f32x4 v = reinterpret_cast<const f32x4*>(in)[i];
  u16x4 o;
  o[0] = f2bf(v[0]); o[1] = f2bf(v[1]); o[2] = f2bf(v[2]); o[3] = f2bf(v[3]);
  reinterpret_cast<u16x4*>(out)[i] = o;
}

// ---------------- transpose W [k][n] -> Wt bf16 [n][k], 3 weights ----------------
__global__ __launch_bounds__(256) void k_transpose(const float* __restrict__ Wq,
                                                   const float* __restrict__ Wk,
                                                   const float* __restrict__ Wv,
                                                   u16* __restrict__ Wt) {
  __shared__ float tile[32][33];
  const float* W = (blockIdx.z == 0) ? Wq : ((blockIdx.z == 1) ? Wk : Wv);
  int n0 = blockIdx.x * 32, k0 = blockIdx.y * 32;
  int tx = threadIdx.x, ty = threadIdx.y;
  #pragma unroll
  for (int r = ty; r < 32; r += 8)
    tile[r][tx] = W[(size_t)(k0 + r) * DIM_ + n0 + tx];
  __syncthreads();
  u16* o = Wt + (size_t)blockIdx.z * DIM_ * DIM_;
  #pragma unroll
  for (int r = ty; r < 32; r += 8)
    o[(size_t)(n0 + r) * DIM_ + k0 + tx] = f2bf(tile[tx][r]);
}

// ---------------- fused QKV GEMM: 256x256 tile, BK=64, 8-phase-style schedule ----------
// 8 waves (2M x 4N), double-buffered 128KB LDS, swizzled slots, counted vmcnt (T3+T4),
// setprio around MFMA clusters (T5). Epilogue: bias + head-split store + L1-L4 coarsen.
__global__ __launch_bounds__(512, 2) void k_qkv_gemm(
    const u16* __restrict__ hid,   // [16384][1024] bf16
    const u16* __restrict__ Wt,    // [3][1024][1024] bf16, n-major (W^T)
    const float* __restrict__ bq, const float* __restrict__ bk, const float* __restrict__ bv,
    u16* __restrict__ qout, u16* __restrict__ kout, u16* __restrict__ vout) {
  const int wsel = blockIdx.z;
  const int m0 = blockIdx.x * 256;
  const int n0 = blockIdx.y * 256;
  __shared__ u16 lds[2][2][16384];   // [dbuf][A/B][256 rows x 64 k], swizzled slots
  const int t = threadIdx.x;
  const int lane = t & 63, wave = t >> 6;
  const int wm = wave >> 2, wn = wave & 3;      // 2 x 4 wave grid
  const int lr = lane & 15, kg = lane >> 4;

  f32x4 acc[8][4];
  #pragma unroll
  for (int f = 0; f < 8; ++f)
    #pragma unroll
    for (int n = 0; n < 4; ++n) acc[f][n] = (f32x4){0.f, 0.f, 0.f, 0.f};

  // ---- staging addressing: thread t covers 16B at row (t>>3), phys slot (t&7); the
  // swizzle (slot ^ row&7) is applied on the GLOBAL source, LDS dest stays linear.
  const int sr = t >> 3;                 // 0..63
  const int slot = (t & 7) ^ (sr & 7);
  const u16* gA = hid + ((size_t)(m0 + sr)) * DIM_ + slot * 8;
  const u16* gB = Wt + (size_t)wsel * DIM_ * DIM_ + ((size_t)(n0 + sr)) * DIM_ + slot * 8;

  auto stageA = [&](int buf, int tile, int half) {
    const u16* s = gA + (size_t)(half * 128) * DIM_ + tile * 64;
    gload_lds16(s, &lds[buf][0][half * 8192 + t * 8]);
    gload_lds16(s + 64 * DIM_, &lds[buf][0][half * 8192 + 4096 + t * 8]);
  };
  auto stageB = [&](int buf, int tile, int half) {
    const u16* s = gB + (size_t)(half * 128) * DIM_ + tile * 64;
    gload_lds16(s, &lds[buf][1][half * 8192 + t * 8]);
    gload_lds16(s + 64 * DIM_, &lds[buf][1][half * 8192 + 4096 + t * 8]);
  };

  // ---- fragment read addressing (row&7 == lr&7 for all frags)
  const int rowA = wm * 128 + lr;
  const int rowB = wn * 64 + lr;
  const int swz0 = ((0 + kg) ^ (lr & 7)) * 8;   // ks = 0
  const int swz1 = ((4 + kg) ^ (lr & 7)) * 8;   // ks = 1

  // ---- prologue: A(0), B(0) into buf0; B(1) into buf1 ----
  stageA(0, 0, 0); stageA(0, 0, 1);
  stageB(0, 0, 0); stageB(0, 0, 1);
  stageB(1, 1, 0); stageB(1, 1, 1);
  asm volatile("s_waitcnt vmcnt(4)" ::: "memory");  // A(0),B(0) landed; B(1) may fly
  SCHED0;
  SBAR;
  SCHED0;

  #pragma unroll 2
  for (int tau = 0; tau < 16; ++tau) {
    const int cur = tau & 1, nxt = cur ^ 1;
    const bool sA = (tau + 1) < 16;
    const bool sB = (tau + 2) < 16;
    bf16x8 af[4], ag[4], bfr0[4], bfr1[4];

    // ---- P0: read A-mh0-ks0 + all B; stage Ah0(tau+1); MFMA mh0 ks0 ----
    #pragma unroll
    for (int mi = 0; mi < 4; ++mi)
      af[mi] = *reinterpret_cast<const bf16x8*>(&lds[cur][0][(rowA + mi * 16) * 64 + swz0]);
    #pragma unroll
    for (int n = 0; n < 4; ++n)
      bfr0[n] = *reinterpret_cast<const bf16x8*>(&lds[cur][1][(rowB + n * 16) * 64 + swz0]);
    #pragma unroll
    for (int n = 0; n < 4; ++n)
      bfr1[n] = *reinterpret_cast<const bf16x8*>(&lds[cur][1][(rowB + n * 16) * 64 + swz1]);
    if (sA) stageA(nxt, tau + 1, 0);
    SBAR;
    __builtin_amdgcn_s_setprio(1);
    #pragma unroll
    for (int mi = 0; mi < 4; ++mi)
      #pragma unroll
      for (int n = 0; n < 4; ++n)
        acc[mi][n] = __builtin_amdgcn_mfma_f32_16x16x32_bf16(af[mi], bfr0[n], acc[mi][n], 0, 0, 0);
    __builtin_amdgcn_s_setprio(0);
    SCHED0; SBAR;

    // ---- P1: read A-mh1-ks0; stage Ah1(tau+1); drain lgkm (B region death); MFMA mh1 ks0 ----
    #pragma unroll
    for (int mi = 0; mi < 4; ++mi)
      ag[mi] = *reinterpret_cast<const bf16x8*>(&lds[cur][0][(rowA + 64 + mi * 16) * 64 + swz0]);
    if (sA) stageA(nxt, tau + 1, 1);
    asm volatile("s_waitcnt lgkmcnt(0)" ::: "memory");  // all this wave's B reads done
    SCHED0;
    SBAR;
    __builtin_amdgcn_s_setprio(1);
    #pragma unroll
    for (int mi = 0; mi < 4; ++mi)
      #pragma unroll
      for (int n = 0; n < 4; ++n)
        acc[4 + mi][n] = __builtin_amdgcn_mfma_f32_16x16x32_bf16(ag[mi], bfr0[n], acc[4 + mi][n], 0, 0, 0);
    __builtin_amdgcn_s_setprio(0);
    SCHED0; SBAR;

    // ---- P2: stage Bh0(tau+2) into buf[cur].B (dead); read A-mh0-ks1; MFMA mh0 ks1 ----
    if (sB) stageB(cur, tau + 2, 0);
    #pragma unroll
    for (int mi = 0; mi < 4; ++mi)
      af[mi] = *reinterpret_cast<const bf16x8*>(&lds[cur][0][(rowA + mi * 16) * 64 + swz1]);
    SBAR;
    __builtin_amdgcn_s_setprio(1);
    #pragma unroll
    for (int mi = 0; mi < 4; ++mi)
      #pragma unroll
      for (int n = 0; n < 4; ++n)
        acc[mi][n] = __builtin_amdgcn_mfma_f32_16x16x32_bf16(af[mi], bfr1[n], acc[mi][n], 0, 0, 0);
    __builtin_amdgcn_s_setprio(0);
    SCHED0; SBAR;

    // ---- P3: stage Bh1(tau+2); read A-mh1-ks1; MFMA mh1 ks1; counted vmcnt; barrier ----
    if (sB) stageB(cur, tau + 2, 1);
    #pragma unroll
    for (int mi = 0; mi < 4; ++mi)
      ag[mi] = *reinterpret_cast<const bf16x8*>(&lds[cur][0][(rowA + 64 + mi * 16) * 64 + swz1]);
    SBAR;
    __builtin_amdgcn_s_setprio(1);
    #pragma unroll
    for (int mi = 0; mi < 4; ++mi)
      #pragma unroll
      for (int n = 0; n < 4; ++n)
        acc[4 + mi][n] = __builtin_amdgcn_mfma_f32_16x16x32_bf16(ag[mi], bfr1[n], acc[4 + mi][n], 0, 0, 0);
    __builtin_amdgcn_s_setprio(0);
    SCHED0;
    if (tau < 15) {
      if (tau == 14) {
        asm volatile("s_waitcnt vmcnt(0)" ::: "memory");  // tail: A(15) must be landed
      } else {
        asm volatile("s_waitcnt vmcnt(4)" ::: "memory");  // leave newest 4 (Bh(tau+2)) in flight
      }
      SCHED0;
      SBAR;
      SCHED0;
    }
  }

  // ---- epilogue: bias + scale, head-split L0 store, L1-L4 coarsen writes ----
  const float* bias = (wsel == 0) ? bq : ((wsel == 1) ? bk : bv);
  u16* dst = (wsel == 0) ? qout : ((wsel == 1) ? kout : vout);
  const float scale = (wsel == 0) ? 0.125f : 1.0f;  // DH^-0.5
  const bool isv = (wsel == 2);
  const float s1 = isv ? 1.f : 0.5f, s2 = isv ? 1.f : 0.25f;
  const float s3 = isv ? 1.f : 0.125f, s4 = isv ? 1.f : 0.0625f;
  const int rg = lane >> 4;
  const int b = m0 >> 12;
  const int posb = m0 & (N_ - 1);
  const int h = (n0 >> 6) + wn;        // one head per wave
  const size_t bh = (size_t)(b * H_ + h);

  #pragma unroll
  for (int f = 0; f < 8; ++f) {
    const int plm = wm * 128 + f * 16;     // fragment pos base (multiple of 16)
    #pragma unroll
    for (int n = 0; n < 4; ++n) {
      const int d = n * 16 + lr;
      const float bias_v = bias[n0 + wn * 64 + d];
      float v0 = (acc[f][n][0] + bias_v) * scale;
      float v1 = (acc[f][n][1] + bias_v) * scale;
      float v2 = (acc[f][n][2] + bias_v) * scale;
      float v3 = (acc[f][n][3] + bias_v) * scale;
      const int pl = plm + rg * 4;
      // L0
      size_t r0 = (bh * N_ + posb + pl) * 64 + d;
      dst[r0] = f2bf(v0); dst[r0 + 64] = f2bf(v1);
      dst[r0 + 128] = f2bf(v2); dst[r0 + 192] = f2bf(v3);
      // L1: row pairs, in-lane
      float c1a = v0 + v1, c1b = v2 + v3;
      size_t r1 = ((size_t)RB1 + bh * 2048 + (size_t)((posb + pl) >> 1)) * 64 + d;
      dst[r1] = f2bf(c1a * s1);
      dst[r1 + 64] = f2bf(c1b * s1);
      // L2: 4-row group, in-lane
      float c2 = c1a + c1b;
      dst[((size_t)RB2 + bh * 1024 + (size_t)((posb + pl) >> 2)) * 64 + d] = f2bf(c2 * s2);
      // L3: 8 rows (rg pair via shfl), L4: 16 rows
      float c3 = c2 + __shfl_xor(c2, 16);
      float c4 = c3 + __shfl_xor(c3, 32);
      if ((rg & 1) == 0)
        dst[((size_t)RB3 + bh * 512 + (size_t)(((posb + plm) >> 3) + (rg >> 1))) * 64 + d] =
            f2bf(c3 * s3);
      if (rg == 0)
        dst[((size_t)RB4 + bh * 256 + (size_t)((posb + plm) >> 4)) * 64 + d] = f2bf(c4 * s4);
    }
  }
}

// ---------------- coarsen pass 2: levels 5..6 from level 4 ----------------
__global__ __launch_bounds__(256) void k_coarsen56(u16* __restrict__ qb, u16* __restrict__ kb,
                                                   u16* __restrict__ vb) {
  int t = blockIdx.x * 256 + threadIdx.x;  // 3*64*64*8 = 98304
  int dg = t & 7;
  int p6 = (t >> 3) & 63;
  int bh = (t >> 9) & 63;
  int z = t >> 15;
  u16* buf = (z == 0) ? qb : ((z == 1) ? kb : vb);
  const bool isv = (z == 2);
  const float s5 = isv ? 1.f : 0.5f, s6 = isv ? 1.f : 0.25f;
  const u16* src = buf + ((size_t)RB4 + bh * 256 + p6 * 4) * 64 + dg * 8;
  float a5[8], a6[8];
  #pragma unroll
  for (int e = 0; e < 8; e++) { a5[e] = 0.f; a6[e] = 0.f; }
  #pragma unroll
  for (int i = 0; i < 4; i++) {
    u16x8 x = *reinterpret_cast<const u16x8*>(src + (size_t)i * 64);
    #pragma unroll
    for (int e = 0; e < 8; e++) a5[e] += bf2f(x[e]);
    if ((i & 1) == 1) {
      u16x8 o;
      #pragma unroll
      for (int e = 0; e < 8; e++) { o[e] = f2bf(a5[e] * s5); a6[e] += a5[e]; a5[e] = 0.f; }
      *reinterpret_cast<u16x8*>(buf + ((size_t)RB5 + bh * 128 + p6 * 2 + (i >> 1)) * 64 + dg * 8) = o;
    }
  }
  u16x8 o;
  #pragma unroll
  for (int e = 0; e < 8; e++) o[e] = f2bf(a6[e] * s6);
  *reinterpret_cast<u16x8*>(buf + ((size_t)RB6 + bh * 64 + p6) * 64 + dg * 8) = o;
}

// ---------------- shared attention core: S = q . K^T (16), A = exp(S - max) ----------------
__device__ __forceinline__ void block_scores(const u16* __restrict__ qp,
                                             const u16* __restrict__ kp,
                                             float* A, float& asum) {
  u16x8 q8[8];
  #pragma unroll
  for (int j = 0; j < 8; j++) q8[j] = *reinterpret_cast<const u16x8*>(qp + j * 8);
  float mx = -3.4e38f;
  #pragma unroll
  for (int c = 0; c < 16; c++) {
    float s = 0.f;
    #pragma unroll
    for (int j = 0; j < 8; j++) {
      u16x8 k8 = *reinterpret_cast<const u16x8*>(kp + c * 64 + j * 8);
      #pragma unroll
      for (int e = 0; e < 8; e++) s += bf2f(q8[j][e]) * bf2f(k8[e]);
    }
    A[c] = s;
    mx = fmaxf(mx, s);
  }
  asum = 0.f;
  #pragma unroll
  for (int c = 0; c < 16; c++) { A[c] = __expf(A[c] - mx); asum += A[c]; }
}

// ---------------- attention levels 1..6, one launch ----------------
__global__ __launch_bounds__(256) void k_attn_rest(
    const u16* __restrict__ qb, const u16* __restrict__ kb, const u16* __restrict__ vb,
    u16* __restrict__ Yb, float* __restrict__ Ab) {
  int gid = blockIdx.x * 256 + threadIdx.x;  // 258048 = 1008*256 exactly
  int r = gid, lnl = 11;
  while (r >= (64 << lnl)) { r -= (64 << lnl); --lnl; }
  int pos = r & ((1 << lnl) - 1);
  size_t row = (size_t)RB1 + gid;
  size_t kvrow = row - pos + ((((pos >> 4) ^ 1) & ((1 << (lnl - 4)) - 1)) << 4);

  float A[16], asum;
  block_scores(qb + row * 64, kb + kvrow * 64, A, asum);
  Ab[gid] = asum;

  const u16* vp = vb + kvrow * 64;
  u16* yp = Yb + (size_t)gid * 64;
  #pragma unroll
  for (int d0 = 0; d0 < 64; d0 += 16) {
    float y[16];
    #pragma unroll
    for (int e = 0; e < 16; e++) y[e] = 0.f;
    #pragma unroll
    for (int c = 0; c < 16; c++) {
      u16x8 v0 = *reinterpret_cast<const u16x8*>(vp + c * 64 + d0);
      u16x8 v1 = *reinterpret_cast<const u16x8*>(vp + c * 64 + d0 + 8);
      float a = A[c];
      #pragma unroll
      for (int e = 0; e < 8; e++) { y[e] += a * bf2f(v0[e]); y[8 + e] += a * bf2f(v1[e]); }
    }
    u16x8 o0, o1;
    #pragma unroll
    for (int e = 0; e < 8; e++) { o0[e] = f2bf(y[e]); o1[e] = f2bf(y[8 + e]); }
    *reinterpret_cast<u16x8*>(yp + d0) = o0;
    *reinterpret_cast<u16x8*>(yp + d0 + 8) = o1;
  }
}

// ---------------- attention level 0 fused with combine ----------------
__global__ __launch_bounds__(256) void k_attn0(
    const u16* __restrict__ qb, const u16* __restrict__ kb, const u16* __restrict__ vb,
    const u16* __restrict__ Yb, const float* __restrict__ Ab, float* __restrict__ out) {
  int gid = blockIdx.x * 256 + threadIdx.x;  // 262144 = 1024*256
  int bh = gid >> 12, pos = gid & 4095;
  size_t row = (size_t)gid;
  size_t kvrow = row - (pos & 15);  // level 0: diagonal block

  float A[16], asum;
  block_scores(qb + row * 64, kb + kvrow * 64, A, asum);

  float den = asum + 1e-8f;
  int ybase[6];
  #pragma unroll
  for (int l = 1; l <= 6; l++) {
    int s = 262144 - (262144 >> (l - 1));  // packed level-l segment start
    int idx = s + (bh << (12 - l)) + (pos >> l);
    den += Ab[idx];
    ybase[l - 1] = idx;
  }
  float inv = 1.0f / den;

  int b = bh >> 4, h = bh & 15;
  float* op = out + ((size_t)(b * N_ + pos)) * DIM_ + h * 64;
  const u16* vp = vb + kvrow * 64;
  #pragma unroll
  for (int d0 = 0; d0 < 64; d0 += 16) {
    float y[16];
    #pragma unroll
    for (int e = 0; e < 16; e++) y[e] = 0.f;
    #pragma unroll
    for (int c = 0; c < 16; c++) {
      u16x8 v0 = *reinterpret_cast<const u16x8*>(vp + c * 64 + d0);
      u16x8 v1 = *reinterpret_cast<const u16x8*>(vp + c * 64 + d0 + 8);
      float a = A[c];
      #pragma unroll
      for (int e = 0; e < 8; e++) { y[e] += a * bf2f(v0[e]); y[8 + e] += a * bf2f(v1[e]); }
    }
    #pragma unroll
    for (int l = 0; l < 6; l++) {
      const u16* yq = Yb + (size_t)ybase[l] * 64 + d0;
      u16x8 c0 = *reinterpret_cast<const u16x8*>(yq);
      u16x8 c1 = *reinterpret_cast<const u16x8*>(yq + 8);
      #pragma unroll
      for (int e = 0; e < 8; e++) { y[e] += bf2f(c0[e]); y[8 + e] += bf2f(c1[e]); }
    }
    f32x4 w0, w1, w2, w3;
    #pragma unroll
    for (int e = 0; e < 4; e++) {
      w0[e] = y[e] * inv; w1[e] = y[4 + e] * inv;
      w2[e] = y[8 + e] * inv; w3[e] = y[12 + e] * inv;
    }
    *reinterpret_cast<f32x4*>(op + d0) = w0;
    *reinterpret_cast<f32x4*>(op + d0 + 4) = w1;
    *reinterpret_cast<f32x4*>(op + d0 + 8) = w2;
    *reinterpret_cast<f32x4*>(op + d0 + 12) = w3;
  }
}

extern "C" void kernel_launch(void* const* d_in, const int* in_sizes, int n_in,
                              void* d_out, int out_size, void* d_ws, size_t ws_size,
                              hipStream_t stream) {
  const float* hid = (const float*)d_in[0];
  const float* Wq = (const float*)d_in[1];
  const float* bq = (const float*)d_in[2];
  const float* Wk = (const float*)d_in[3];
  const float* bk = (const float*)d_in[4];
  const float* Wv = (const float*)d_in[5];
  const float* bv = (const float*)d_in[6];
  float* out = (float*)d_out;
  char* ws = (char*)d_ws;

  // workspace (high-water 239,599,616 B):
  //   phase 1 (GEMM):  hidb [0, 33554432)   Wt [33554432, 39845888)
  //   phase 2 (attn):  Yb   [0, 33030144)   Ab [33030144, 34062336)   <- aliases dead hidb/Wt
  //   both:            qb [39845888) kb [106430464) vb [173015040) .. 239599616
  u16* hidb = (u16*)(ws + 0);
  u16* Wt   = (u16*)(ws + 33554432);
  u16* Yb   = (u16*)(ws + 0);           // bf16, levels 1..6 packed (258048 rows x 64)
  float* Ab = (float*)(ws + 33030144);  // fp32, levels 1..6 packed (258048)
  u16* qb   = (u16*)(ws + 39845888);
  u16* kb   = (u16*)(ws + 106430464);
  u16* vb   = (u16*)(ws + 173015040);

  k_hid2bf<<<16384, 256, 0, stream>>>(hid, hidb, MTOK * DIM_ / 4);
  k_transpose<<<dim3(32, 32, 3), dim3(32, 8, 1), 0, stream>>>(Wq, Wk, Wv, Wt);
  k_qkv_gemm<<<dim3(64, 4, 3), 512, 0, stream>>>(hidb, Wt, bq, bk, bv, qb, kb, vb);
  k_coarsen56<<<384, 256, 0, stream>>>(qb, kb, vb);
  k_attn_rest<<<1008, 256, 0, stream>>>(qb, kb, vb, Yb, Ab);
  k_attn0<<<1024, 256, 0, stream>>>(qb, kb, vb, Yb, Ab, out);
}